// Round 4
// baseline (219.133 us; speedup 1.0000x reference)
//
#include <hip/hip_runtime.h>
#include <math.h>

#define N_NODES 40000
#define N_EDGES 640000
#define SCAN_BLOCKS ((N_NODES + 255) / 256)   // 157
#define FILLB (N_EDGES / 256)                  // 2500 fill blocks
#define GB1X 313                               // gemm1 x-blocks (313*4 waves*32 rows >= 40000)

typedef __attribute__((ext_vector_type(8))) short short8;   // 8 bf16 (A/B frag)
typedef __attribute__((ext_vector_type(4))) float f32x4;    // C/D frag

__device__ __forceinline__ unsigned short f2bf(float f) {
    union { float f; unsigned u; } v; v.f = f;
    unsigned r = (v.u + 0x7FFFu + ((v.u >> 16) & 1u)) >> 16;  // RNE
    return (unsigned short)r;
}
__device__ __forceinline__ float bf2f(unsigned short h) {
    union { unsigned u; float f; } v; v.u = ((unsigned)h) << 16;
    return v.f;
}

__device__ __forceinline__ float wave_sum(float v) {
    #pragma unroll
    for (int m = 1; m < 64; m <<= 1) v += __shfl_xor(v, m, 64);
    return v;
}
__device__ __forceinline__ float wave_max(float v) {
    #pragma unroll
    for (int m = 1; m < 64; m <<= 1) v = fmaxf(v, __shfl_xor(v, m, 64));
    return v;
}

// Fused: blocks [0,10000): h0 = LN(x) -> bf16 hi/lo planes
//        blocks [10000,10168): weight transpose+split
//        blocks [10168,10325): zero deg
__global__ __launch_bounds__(256) void combo0_kernel(const float* __restrict__ x,
        const float* __restrict__ g, const float* __restrict__ b,
        unsigned short* __restrict__ h0h, unsigned short* __restrict__ h0l,
        const float* __restrict__ W0l, const float* __restrict__ W0r,
        const float* __restrict__ W1l, const float* __restrict__ W1r,
        unsigned short* __restrict__ Wt1h, unsigned short* __restrict__ Wt1l,
        unsigned short* __restrict__ Wt2h, unsigned short* __restrict__ Wt2l,
        int* __restrict__ deg) {
    int bid = blockIdx.x;
    if (bid < 10000) {
        int row = bid * 4 + (threadIdx.x >> 6);
        int lane = threadIdx.x & 63;
        float2 v = ((const float2*)(x + (size_t)row * 128))[lane];
        float mu = wave_sum(v.x + v.y) * (1.0f / 128.0f);
        float dx = v.x - mu, dy = v.y - mu;
        float var = wave_sum(dx * dx + dy * dy) * (1.0f / 128.0f);
        float rs = rsqrtf(var + 1e-5f);
        float2 gv = ((const float2*)g)[lane];
        float2 bv = ((const float2*)b)[lane];
        float ox = dx * rs * gv.x + bv.x;
        float oy = dy * rs * gv.y + bv.y;
        ushort2 hv, lv;
        hv.x = f2bf(ox); hv.y = f2bf(oy);
        lv.x = f2bf(ox - bf2f(hv.x)); lv.y = f2bf(oy - bf2f(hv.y));
        ((ushort2*)(h0h + (size_t)row * 128))[lane] = hv;
        ((ushort2*)(h0l + (size_t)row * 128))[lane] = lv;
    } else if (bid < 10168) {
        int i = (bid - 10000) * 256 + threadIdx.x;   // 0..43007
        float w; unsigned short *ph, *pl; int idx;
        if (i < 256 * 128) {
            int c = i >> 7, k = i & 127;
            w = (c < 128) ? W0l[c * 128 + k] : W0r[(c - 128) * 128 + k];
            ph = Wt1h; pl = Wt1l; idx = i;
        } else {
            int j = i - 256 * 128;
            int c = j >> 7, k = j & 127;
            w = (c < 40) ? W1l[c * 128 + k] : W1r[(c - 40) * 128 + k];
            ph = Wt2h; pl = Wt2l; idx = j;
        }
        unsigned short hi = f2bf(w);
        ph[idx] = hi;
        pl[idx] = f2bf(w - bf2f(hi));
    } else {
        int i = (bid - 10168) * 256 + threadIdx.x;
        if (i < N_NODES) deg[i] = 0;
    }
}

// ---------------- CSR-by-destination build ----------------

__global__ __launch_bounds__(256) void deg_kernel(const int* __restrict__ ei,
        int* __restrict__ deg) {
    int e = blockIdx.x * 256 + threadIdx.x;
    atomicAdd(&deg[ei[N_EDGES + e]], 1);
}

__global__ __launch_bounds__(256) void scanA(const int* __restrict__ deg,
        int* __restrict__ rowStart, int* __restrict__ blockSums) {
    int i = blockIdx.x * 256 + threadIdx.x;
    int lane = threadIdx.x & 63, wid = threadIdx.x >> 6;
    int v = (i < N_NODES) ? deg[i] : 0;
    int s = v;
    #pragma unroll
    for (int m = 1; m < 64; m <<= 1) {
        int u = __shfl_up(s, m, 64);
        if (lane >= m) s += u;
    }
    __shared__ int wsum[4];
    if (lane == 63) wsum[wid] = s;
    __syncthreads();
    int off = 0;
    for (int w = 0; w < wid; ++w) off += wsum[w];
    if (i < N_NODES) rowStart[i] = off + s - v;
    if (threadIdx.x == 255) blockSums[blockIdx.x] = off + s;
}

__global__ __launch_bounds__(256) void scanB(const int* __restrict__ blockSums,
        int* __restrict__ blockOffs) {
    int t = threadIdx.x;
    int lane = t & 63, wid = t >> 6;
    int v = (t < SCAN_BLOCKS) ? blockSums[t] : 0;
    int s = v;
    #pragma unroll
    for (int m = 1; m < 64; m <<= 1) {
        int u = __shfl_up(s, m, 64);
        if (lane >= m) s += u;
    }
    __shared__ int wsum[4];
    if (lane == 63) wsum[wid] = s;
    __syncthreads();
    int off = 0;
    for (int w = 0; w < wid; ++w) off += wsum[w];
    blockOffs[t] = off + s - v;
}

__global__ __launch_bounds__(256) void scanC(const int* __restrict__ blockOffs,
        int* __restrict__ rowStart, int* __restrict__ cursor) {
    int i = blockIdx.x * 256 + threadIdx.x;
    if (i < N_NODES) {
        int v = rowStart[i] + blockOffs[blockIdx.x];
        rowStart[i] = v;
        cursor[i] = v;
    }
    if (i == 0) rowStart[N_NODES] = N_EDGES;
}

// ---------------- fused fill (edge bucket-sort) + gemm1 (MFMA bf16x3) ----------
// fill blocks [0, FILLB): sPk[cursor[d]++] = src | bf16(w)<<16
// gemm blocks [FILLB, FILLB+626):
//   A: lane holds x[rBase + (lane&15)][kb + (lane>>4)*8 + j]
//   B: lane holds W[ct*16 + (lane&15)][kb + (lane>>4)*8 + j]  (col-major planes)
//   C/D: col = lane&15, row = (lane>>4)*4 + reg
//   hl(bf16, bias folded) = h0@W0l^T + b0l (cols 0..127); agg(fp32) = h0@W0r^T
__global__ __launch_bounds__(256) void mega1_kernel(
        const int* __restrict__ ei, const float* __restrict__ ew,
        int* __restrict__ cursor, unsigned int* __restrict__ sPk,
        const unsigned short* __restrict__ h0h, const unsigned short* __restrict__ h0l,
        const unsigned short* __restrict__ Wt1h, const unsigned short* __restrict__ Wt1l,
        const float* __restrict__ b0l,
        unsigned short* __restrict__ hl, float* __restrict__ agg) {
    int bid = blockIdx.x;
    if (bid < FILLB) {
        int e = bid * 256 + threadIdx.x;
        int s = ei[e];
        int d = ei[N_EDGES + e];
        unsigned int pk = (unsigned int)s | ((unsigned int)f2bf(ew[e]) << 16);
        int idx = atomicAdd(&cursor[d], 1);
        sPk[idx] = pk;
        return;
    }
    int gb = bid - FILLB;                 // 0..625
    int gy = (gb >= GB1X) ? 1 : 0;
    int gx = gb - gy * GB1X;
    int wid = threadIdx.x >> 6, lane = threadIdx.x & 63;
    int rBase = (gx * 4 + wid) * 32;
    if (rBase >= N_NODES) return;
    int cBase = gy * 128;
    int lr = lane & 15;
    int lk = (lane >> 4) * 8;
    const unsigned short* a0h = h0h + (size_t)(rBase + lr) * 128 + lk;
    const unsigned short* a0l = h0l + (size_t)(rBase + lr) * 128 + lk;
    const unsigned short* a1h = a0h + 16 * 128;
    const unsigned short* a1l = a0l + 16 * 128;
    f32x4 acc[2][8] = {};
    #pragma unroll
    for (int ks = 0; ks < 4; ++ks) {
        int kb = ks * 32;
        short8 A0h = *(const short8*)(a0h + kb);
        short8 A0l = *(const short8*)(a0l + kb);
        short8 A1h = *(const short8*)(a1h + kb);
        short8 A1l = *(const short8*)(a1l + kb);
        #pragma unroll
        for (int ct = 0; ct < 8; ++ct) {
            size_t boff = (size_t)(cBase + ct * 16 + lr) * 128 + lk + kb;
            short8 Bh = *(const short8*)(Wt1h + boff);
            short8 Bl = *(const short8*)(Wt1l + boff);
            acc[0][ct] = __builtin_amdgcn_mfma_f32_16x16x32_bf16(A0h, Bh, acc[0][ct], 0, 0, 0);
            acc[0][ct] = __builtin_amdgcn_mfma_f32_16x16x32_bf16(A0h, Bl, acc[0][ct], 0, 0, 0);
            acc[0][ct] = __builtin_amdgcn_mfma_f32_16x16x32_bf16(A0l, Bh, acc[0][ct], 0, 0, 0);
            acc[1][ct] = __builtin_amdgcn_mfma_f32_16x16x32_bf16(A1h, Bh, acc[1][ct], 0, 0, 0);
            acc[1][ct] = __builtin_amdgcn_mfma_f32_16x16x32_bf16(A1h, Bl, acc[1][ct], 0, 0, 0);
            acc[1][ct] = __builtin_amdgcn_mfma_f32_16x16x32_bf16(A1l, Bh, acc[1][ct], 0, 0, 0);
        }
    }
    int orow = (lane >> 4) * 4;
    #pragma unroll
    for (int rt = 0; rt < 2; ++rt) {
        int row = rBase + rt * 16 + orow;
        #pragma unroll
        for (int ct = 0; ct < 8; ++ct) {
            int col = cBase + ct * 16 + lr;
            if (col < 128) {
                float bias = b0l[col];
                #pragma unroll
                for (int j = 0; j < 4; ++j)
                    hl[(size_t)(row + j) * 128 + col] = f2bf(acc[rt][ct][j] + bias);
            } else {
                int cc = col - 128;
                #pragma unroll
                for (int j = 0; j < 4; ++j)
                    agg[(size_t)(row + j) * 128 + cc] = acc[rt][ct][j];
            }
        }
    }
}

// gl(bf16, bias folded) = h2@W1l^T + b1l (cols 0..39); agg2(fp32) = h2@W1r^T
__global__ __launch_bounds__(256) void gemm2_kernel(
        const unsigned short* __restrict__ h2h, const unsigned short* __restrict__ h2l,
        const unsigned short* __restrict__ Wt2h, const unsigned short* __restrict__ Wt2l,
        const float* __restrict__ b1l,
        unsigned short* __restrict__ gl, float* __restrict__ agg2) {
    int wid = threadIdx.x >> 6, lane = threadIdx.x & 63;
    int rBase = (blockIdx.x * 4 + wid) * 32;
    if (rBase >= N_NODES) return;
    int lr = lane & 15;
    int lk = (lane >> 4) * 8;
    const unsigned short* a0h = h2h + (size_t)(rBase + lr) * 128 + lk;
    const unsigned short* a0l = h2l + (size_t)(rBase + lr) * 128 + lk;
    const unsigned short* a1h = a0h + 16 * 128;
    const unsigned short* a1l = a0l + 16 * 128;
    f32x4 acc[2][5] = {};
    #pragma unroll
    for (int ks = 0; ks < 4; ++ks) {
        int kb = ks * 32;
        short8 A0h = *(const short8*)(a0h + kb);
        short8 A0l = *(const short8*)(a0l + kb);
        short8 A1h = *(const short8*)(a1h + kb);
        short8 A1l = *(const short8*)(a1l + kb);
        #pragma unroll
        for (int ct = 0; ct < 5; ++ct) {
            size_t boff = (size_t)(ct * 16 + lr) * 128 + lk + kb;
            short8 Bh = *(const short8*)(Wt2h + boff);
            short8 Bl = *(const short8*)(Wt2l + boff);
            acc[0][ct] = __builtin_amdgcn_mfma_f32_16x16x32_bf16(A0h, Bh, acc[0][ct], 0, 0, 0);
            acc[0][ct] = __builtin_amdgcn_mfma_f32_16x16x32_bf16(A0h, Bl, acc[0][ct], 0, 0, 0);
            acc[0][ct] = __builtin_amdgcn_mfma_f32_16x16x32_bf16(A0l, Bh, acc[0][ct], 0, 0, 0);
            acc[1][ct] = __builtin_amdgcn_mfma_f32_16x16x32_bf16(A1h, Bh, acc[1][ct], 0, 0, 0);
            acc[1][ct] = __builtin_amdgcn_mfma_f32_16x16x32_bf16(A1h, Bl, acc[1][ct], 0, 0, 0);
            acc[1][ct] = __builtin_amdgcn_mfma_f32_16x16x32_bf16(A1l, Bh, acc[1][ct], 0, 0, 0);
        }
    }
    int orow = (lane >> 4) * 4;
    #pragma unroll
    for (int rt = 0; rt < 2; ++rt) {
        int row = rBase + rt * 16 + orow;
        #pragma unroll
        for (int ct = 0; ct < 5; ++ct) {
            int col = ct * 16 + lr;   // 0..79
            if (col < 40) {
                float bias = b1l[col];
                #pragma unroll
                for (int j = 0; j < 4; ++j)
                    gl[(size_t)(row + j) * 40 + col] = f2bf(acc[rt][ct][j] + bias);
            } else {
                int cc = col - 40;
                #pragma unroll
                for (int j = 0; j < 4; ++j)
                    agg2[(size_t)(row + j) * 40 + cc] = acc[rt][ct][j];
            }
        }
    }
}

// gather bf16 messages + fused l2norm+LN+relu -> split-bf16 h2; wave per node
__global__ __launch_bounds__(256) void gather1_kernel(const int* __restrict__ rowStart,
        const unsigned int* __restrict__ sPk, const unsigned short* __restrict__ hl,
        const float* __restrict__ agg,
        const float* __restrict__ g, const float* __restrict__ b,
        unsigned short* __restrict__ h2h, unsigned short* __restrict__ h2l) {
    int row = blockIdx.x * 4 + (threadIdx.x >> 6);
    int lane = threadIdx.x & 63;
    int beg = rowStart[row], end = rowStart[row + 1];
    float2 acc = ((const float2*)(agg + (size_t)row * 128))[lane];  // root term
    int e = beg;
    for (; e + 4 <= end; e += 4) {
        unsigned int p0 = sPk[e], p1 = sPk[e + 1], p2 = sPk[e + 2], p3 = sPk[e + 3];
        // issue all 4 row loads before the FMA chain (outstanding-load depth)
        ushort2 u0 = ((const ushort2*)(hl + (size_t)(p0 & 0xFFFF) * 128))[lane];
        ushort2 u1 = ((const ushort2*)(hl + (size_t)(p1 & 0xFFFF) * 128))[lane];
        ushort2 u2 = ((const ushort2*)(hl + (size_t)(p2 & 0xFFFF) * 128))[lane];
        ushort2 u3 = ((const ushort2*)(hl + (size_t)(p3 & 0xFFFF) * 128))[lane];
        float w0 = bf2f((unsigned short)(p0 >> 16));
        float w1 = bf2f((unsigned short)(p1 >> 16));
        float w2 = bf2f((unsigned short)(p2 >> 16));
        float w3 = bf2f((unsigned short)(p3 >> 16));
        acc.x = fmaf(bf2f(u0.x), w0, acc.x); acc.y = fmaf(bf2f(u0.y), w0, acc.y);
        acc.x = fmaf(bf2f(u1.x), w1, acc.x); acc.y = fmaf(bf2f(u1.y), w1, acc.y);
        acc.x = fmaf(bf2f(u2.x), w2, acc.x); acc.y = fmaf(bf2f(u2.y), w2, acc.y);
        acc.x = fmaf(bf2f(u3.x), w3, acc.x); acc.y = fmaf(bf2f(u3.y), w3, acc.y);
    }
    for (; e < end; ++e) {
        unsigned int p = sPk[e];
        ushort2 u = ((const ushort2*)(hl + (size_t)(p & 0xFFFF) * 128))[lane];
        float w = bf2f((unsigned short)(p >> 16));
        acc.x = fmaf(bf2f(u.x), w, acc.x);
        acc.y = fmaf(bf2f(u.y), w, acc.y);
    }
    // fused: l2normalize -> LN -> relu -> bf16 hi/lo split
    float nrm = sqrtf(wave_sum(acc.x * acc.x + acc.y * acc.y));
    float inv = 1.0f / fmaxf(nrm, 1e-12f);
    float vx = acc.x * inv, vy = acc.y * inv;
    float mu = wave_sum(vx + vy) * (1.0f / 128.0f);
    float dx = vx - mu, dy = vy - mu;
    float var = wave_sum(dx * dx + dy * dy) * (1.0f / 128.0f);
    float rs = rsqrtf(var + 1e-5f);
    float2 gv = ((const float2*)g)[lane];
    float2 bv = ((const float2*)b)[lane];
    float ox = fmaxf(dx * rs * gv.x + bv.x, 0.0f);
    float oy = fmaxf(dy * rs * gv.y + bv.y, 0.0f);
    ushort2 hv, lv;
    hv.x = f2bf(ox); hv.y = f2bf(oy);
    lv.x = f2bf(ox - bf2f(hv.x)); lv.y = f2bf(oy - bf2f(hv.y));
    ((ushort2*)(h2h + (size_t)row * 128))[lane] = hv;
    ((ushort2*)(h2l + (size_t)row * 128))[lane] = lv;
}

// gather bf16 messages + fused l2norm + log_softmax; wave per node, lanes 0..39
__global__ __launch_bounds__(256) void gather2_kernel(const int* __restrict__ rowStart,
        const unsigned int* __restrict__ sPk, const unsigned short* __restrict__ gl,
        const float* __restrict__ agg2, float* __restrict__ out) {
    int row = blockIdx.x * 4 + (threadIdx.x >> 6);
    int lane = threadIdx.x & 63;
    bool act = lane < 40;
    int beg = rowStart[row], end = rowStart[row + 1];
    float acc = act ? agg2[(size_t)row * 40 + lane] : 0.0f;  // root term
    int e = beg;
    for (; e + 2 <= end; e += 2) {
        unsigned int p0 = sPk[e], p1 = sPk[e + 1];
        if (act) {
            float v0 = bf2f(gl[(size_t)(p0 & 0xFFFF) * 40 + lane]);
            float v1 = bf2f(gl[(size_t)(p1 & 0xFFFF) * 40 + lane]);
            acc = fmaf(v0, bf2f((unsigned short)(p0 >> 16)), acc);
            acc = fmaf(v1, bf2f((unsigned short)(p1 >> 16)), acc);
        }
    }
    if (e < end) {
        unsigned int p = sPk[e];
        if (act) {
            float v = bf2f(gl[(size_t)(p & 0xFFFF) * 40 + lane]);
            acc = fmaf(v, bf2f((unsigned short)(p >> 16)), acc);
        }
    }
    float nrm = sqrtf(wave_sum(act ? acc * acc : 0.0f));
    float o = acc / fmaxf(nrm, 1e-12f);
    float m = wave_max(act ? o : -INFINITY);
    float s = wave_sum(act ? expf(o - m) : 0.0f);
    float ls = logf(s);
    if (act) out[(size_t)row * 40 + lane] = o - m - ls;
}

extern "C" void kernel_launch(void* const* d_in, const int* in_sizes, int n_in,
                              void* d_out, int out_size, void* d_ws, size_t ws_size,
                              hipStream_t stream) {
    const float* x    = (const float*)d_in[0];
    const int*   ei   = (const int*)d_in[1];
    const float* ew   = (const float*)d_in[2];
    const float* ln0g = (const float*)d_in[3];
    const float* ln0b = (const float*)d_in[4];
    const float* W0l  = (const float*)d_in[5];
    const float* b0l  = (const float*)d_in[6];
    const float* W0r  = (const float*)d_in[7];
    const float* ln1g = (const float*)d_in[8];
    const float* ln1b = (const float*)d_in[9];
    const float* W1l  = (const float*)d_in[10];
    const float* b1l  = (const float*)d_in[11];
    const float* W1r  = (const float*)d_in[12];
    float* out = (float*)d_out;

    const size_t NBUF = (size_t)N_NODES * 128;  // 5.12M elems
    char* p = (char*)d_ws;
    auto alloc = [&](size_t bytes) { char* r = p; p += (bytes + 255) & ~(size_t)255; return r; };
    float*          agg  = (float*)alloc(NBUF * 4);          // agg / agg2 (fp32)
    unsigned short* hl   = (unsigned short*)alloc(NBUF * 2); // hl / gl (bf16)
    unsigned short* h0h  = (unsigned short*)alloc(NBUF * 2); // h0 hi / h2 hi
    unsigned short* h0l  = (unsigned short*)alloc(NBUF * 2); // h0 lo / h2 lo
    unsigned short* Wt1h = (unsigned short*)alloc(256 * 128 * 2);
    unsigned short* Wt1l = (unsigned short*)alloc(256 * 128 * 2);
    unsigned short* Wt2h = (unsigned short*)alloc(80 * 128 * 2);
    unsigned short* Wt2l = (unsigned short*)alloc(80 * 128 * 2);
    unsigned int*   sPk  = (unsigned int*)alloc((size_t)N_EDGES * 4);
    int*            deg  = (int*)alloc(N_NODES * 4);
    int*       rowStart  = (int*)alloc((N_NODES + 1) * 4);
    int*         cursor  = (int*)alloc(N_NODES * 4);
    int*      blockSums  = (int*)alloc(256 * 4);
    int*      blockOffs  = (int*)alloc(256 * 4);
    unsigned short* gl   = hl;    // hl dead after gather1
    float*        agg2   = agg;   // agg dead after gather1

    // --- fused LN0 + weight prep + deg zero ---
    combo0_kernel<<<10000 + 168 + SCAN_BLOCKS, 256, 0, stream>>>(x, ln0g, ln0b,
            h0h, h0l, W0l, W0r, W1l, W1r, Wt1h, Wt1l, Wt2h, Wt2l, deg);
    // --- CSR build ---
    deg_kernel<<<N_EDGES / 256, 256, 0, stream>>>(ei, deg);
    scanA<<<SCAN_BLOCKS, 256, 0, stream>>>(deg, rowStart, blockSums);
    scanB<<<1, 256, 0, stream>>>(blockSums, blockOffs);
    scanC<<<SCAN_BLOCKS, 256, 0, stream>>>(blockOffs, rowStart, cursor);

    // --- fused fill + gemm1 (both latency-bound; co-scheduled) ---
    mega1_kernel<<<FILLB + 2 * GB1X, 256, 0, stream>>>(ei, ew, cursor, sPk,
            h0h, h0l, Wt1h, Wt1l, b0l, hl, agg);

    gather1_kernel<<<N_NODES / 4, 256, 0, stream>>>(rowStart, sPk, hl, agg,
                                                    ln1g, ln1b, h0h, h0l);
    gemm2_kernel<<<313, 256, 0, stream>>>(h0h, h0l, Wt2h, Wt2l, b1l, gl, agg2);
    gather2_kernel<<<N_NODES / 4, 256, 0, stream>>>(rowStart, sPk, gl, agg2, out);
}

// Round 5
// 184.286 us; speedup vs baseline: 1.1891x; 1.1891x over previous
//
#include <hip/hip_runtime.h>
#include <math.h>

#define N_NODES 40000
#define N_EDGES 640000
#define SCAN_BLOCKS ((N_NODES + 255) / 256)   // 157
#define FILLB (N_EDGES / 256)                 // 2500

typedef __attribute__((ext_vector_type(8))) short short8;   // 8 bf16 (A/B frag)
typedef __attribute__((ext_vector_type(4))) float f32x4;    // C/D frag

__device__ __forceinline__ unsigned short f2bf(float f) {
    union { float f; unsigned u; } v; v.f = f;
    unsigned r = (v.u + 0x7FFFu + ((v.u >> 16) & 1u)) >> 16;  // RNE
    return (unsigned short)r;
}
__device__ __forceinline__ float bf2f(unsigned short h) {
    union { unsigned u; float f; } v; v.u = ((unsigned)h) << 16;
    return v.f;
}

__device__ __forceinline__ float wave_sum(float v) {
    #pragma unroll
    for (int m = 1; m < 64; m <<= 1) v += __shfl_xor(v, m, 64);
    return v;
}
__device__ __forceinline__ float wave_max(float v) {
    #pragma unroll
    for (int m = 1; m < 64; m <<= 1) v = fmaxf(v, __shfl_xor(v, m, 64));
    return v;
}

__global__ __launch_bounds__(256) void zero_deg(int* __restrict__ deg) {
    int i = blockIdx.x * 256 + threadIdx.x;
    if (i < N_NODES) deg[i] = 0;
}

// Interleaved fusion (every 5th block = deg histogram; rest = LN0 / weight prep):
//   deg blocks:   db = bid/5 in [0,2500)
//   combo blocks: cb = bid - bid/5; cb<10000 -> LN rows, cb<10168 -> weight prep
__global__ __launch_bounds__(256) void comboDeg_kernel(const float* __restrict__ x,
        const float* __restrict__ g, const float* __restrict__ b,
        unsigned short* __restrict__ h0h, unsigned short* __restrict__ h0l,
        const float* __restrict__ W0l, const float* __restrict__ W0r,
        const float* __restrict__ W1l, const float* __restrict__ W1r,
        unsigned short* __restrict__ Wt1h, unsigned short* __restrict__ Wt1l,
        unsigned short* __restrict__ Wt2h, unsigned short* __restrict__ Wt2l,
        int* __restrict__ deg, const int* __restrict__ ei) {
    int bid = blockIdx.x;
    if ((bid % 5) == 4) {
        int db = bid / 5;
        if (db < FILLB) {
            int e = db * 256 + threadIdx.x;
            atomicAdd(&deg[ei[N_EDGES + e]], 1);
        }
        return;
    }
    int cb = bid - bid / 5;
    if (cb < 10000) {
        int row = cb * 4 + (threadIdx.x >> 6);
        int lane = threadIdx.x & 63;
        float2 v = ((const float2*)(x + (size_t)row * 128))[lane];
        float mu = wave_sum(v.x + v.y) * (1.0f / 128.0f);
        float dx = v.x - mu, dy = v.y - mu;
        float var = wave_sum(dx * dx + dy * dy) * (1.0f / 128.0f);
        float rs = rsqrtf(var + 1e-5f);
        float2 gv = ((const float2*)g)[lane];
        float2 bv = ((const float2*)b)[lane];
        float ox = dx * rs * gv.x + bv.x;
        float oy = dy * rs * gv.y + bv.y;
        ushort2 hv, lv;
        hv.x = f2bf(ox); hv.y = f2bf(oy);
        lv.x = f2bf(ox - bf2f(hv.x)); lv.y = f2bf(oy - bf2f(hv.y));
        ((ushort2*)(h0h + (size_t)row * 128))[lane] = hv;
        ((ushort2*)(h0l + (size_t)row * 128))[lane] = lv;
    } else if (cb < 10168) {
        int i = (cb - 10000) * 256 + threadIdx.x;   // 0..43007
        float w; unsigned short *ph, *pl; int idx;
        if (i < 256 * 128) {
            int c = i >> 7, k = i & 127;
            w = (c < 128) ? W0l[c * 128 + k] : W0r[(c - 128) * 128 + k];
            ph = Wt1h; pl = Wt1l; idx = i;
        } else {
            int j = i - 256 * 128;
            int c = j >> 7, k = j & 127;
            w = (c < 40) ? W1l[c * 128 + k] : W1r[(c - 40) * 128 + k];
            ph = Wt2h; pl = Wt2l; idx = j;
        }
        unsigned short hi = f2bf(w);
        ph[idx] = hi;
        pl[idx] = f2bf(w - bf2f(hi));
    }
}

// ---------------- CSR scans ----------------

__global__ __launch_bounds__(256) void scanA(const int* __restrict__ deg,
        int* __restrict__ rowStart, int* __restrict__ blockSums) {
    int i = blockIdx.x * 256 + threadIdx.x;
    int lane = threadIdx.x & 63, wid = threadIdx.x >> 6;
    int v = (i < N_NODES) ? deg[i] : 0;
    int s = v;
    #pragma unroll
    for (int m = 1; m < 64; m <<= 1) {
        int u = __shfl_up(s, m, 64);
        if (lane >= m) s += u;
    }
    __shared__ int wsum[4];
    if (lane == 63) wsum[wid] = s;
    __syncthreads();
    int off = 0;
    for (int w = 0; w < wid; ++w) off += wsum[w];
    if (i < N_NODES) rowStart[i] = off + s - v;
    if (threadIdx.x == 255) blockSums[blockIdx.x] = off + s;
}

__global__ __launch_bounds__(256) void scanB(const int* __restrict__ blockSums,
        int* __restrict__ blockOffs) {
    int t = threadIdx.x;
    int lane = t & 63, wid = t >> 6;
    int v = (t < SCAN_BLOCKS) ? blockSums[t] : 0;
    int s = v;
    #pragma unroll
    for (int m = 1; m < 64; m <<= 1) {
        int u = __shfl_up(s, m, 64);
        if (lane >= m) s += u;
    }
    __shared__ int wsum[4];
    if (lane == 63) wsum[wid] = s;
    __syncthreads();
    int off = 0;
    for (int w = 0; w < wid; ++w) off += wsum[w];
    blockOffs[t] = off + s - v;
}

__global__ __launch_bounds__(256) void scanC(const int* __restrict__ blockOffs,
        int* __restrict__ rowStart, int* __restrict__ cursor) {
    int i = blockIdx.x * 256 + threadIdx.x;
    if (i < N_NODES) {
        int v = rowStart[i] + blockOffs[blockIdx.x];
        rowStart[i] = v;
        cursor[i] = v;
    }
    if (i == 0) rowStart[N_NODES] = N_EDGES;
}

// bucket-fill packed edges: low16 = src, high16 = bf16(weight)
__global__ __launch_bounds__(256) void fill_kernel(const int* __restrict__ ei,
        const float* __restrict__ ew, int* __restrict__ cursor,
        unsigned int* __restrict__ sPk) {
    int e = blockIdx.x * 256 + threadIdx.x;
    int s = ei[e];
    int d = ei[N_EDGES + e];
    unsigned int pk = (unsigned int)s | ((unsigned int)f2bf(ew[e]) << 16);
    int idx = atomicAdd(&cursor[d], 1);
    sPk[idx] = pk;
}

// ---------------- MFMA GEMMs, B staged in LDS (XOR-swizzled) ----------------
// LDS element (c,k) lives at byte (c*256 + k*2) ^ ((c&7)<<4)  [swizzle in bits 4-6;
// 16B granules along k are XOR-invariant below bit 4, so frag reads stay contiguous].
// B frag read (lanes 0-15 stride 256B) becomes 2-way bank aliasing = free.
// A frags straight from global (4 loads per K-step, streaming rows).
// C/D: col = lane&15, row = (lane>>4)*4 + reg   [HW-verified]

// hl(bf16, bias folded) = h0@W0l^T + b0l (cols 0..127); agg(fp32) = h0@W0r^T
__global__ __launch_bounds__(256) void gemm1_kernel(
        const unsigned short* __restrict__ h0h, const unsigned short* __restrict__ h0l,
        const unsigned short* __restrict__ Wt1h, const unsigned short* __restrict__ Wt1l,
        const float* __restrict__ b0l,
        unsigned short* __restrict__ hl, float* __restrict__ agg) {
    __shared__ unsigned short Bs[2][128 * 128];   // 64 KB: [plane][c*128+k] swizzled
    int tid = threadIdx.x;
    int cBase = blockIdx.y * 128;
    #pragma unroll
    for (int plane = 0; plane < 2; ++plane) {
        const unsigned short* src = plane ? Wt1l : Wt1h;
        char* dst = (char*)Bs[plane];
        #pragma unroll
        for (int i = 0; i < 8; ++i) {
            int gid = i * 256 + tid;            // 0..2047
            int c = gid >> 4, kc = gid & 15;    // c in [0,128), kc in [0,16)
            short8 v = *(const short8*)(src + (size_t)(cBase + c) * 128 + kc * 8);
            int byte = (c * 256 + kc * 16) ^ ((c & 7) << 4);
            *(short8*)(dst + byte) = v;
        }
    }
    __syncthreads();

    int wid = tid >> 6, lane = tid & 63;
    int rBase = (blockIdx.x * 4 + wid) * 32;
    if (rBase < N_NODES) {
        int lr = lane & 15;
        int lk = (lane >> 4) * 8;
        int sw = (lr & 7) << 4;
        const unsigned short* a0h = h0h + (size_t)(rBase + lr) * 128 + lk;
        const unsigned short* a0l = h0l + (size_t)(rBase + lr) * 128 + lk;
        const unsigned short* a1h = a0h + 16 * 128;
        const unsigned short* a1l = a0l + 16 * 128;
        f32x4 acc[2][8] = {};
        #pragma unroll
        for (int ks = 0; ks < 4; ++ks) {
            int kb = ks * 32;
            short8 A0h = *(const short8*)(a0h + kb);
            short8 A0l = *(const short8*)(a0l + kb);
            short8 A1h = *(const short8*)(a1h + kb);
            short8 A1l = *(const short8*)(a1l + kb);
            #pragma unroll
            for (int ct = 0; ct < 8; ++ct) {
                int bb = (((ct * 16 + lr) << 8) + (ks << 6) + ((lane >> 4) << 4)) ^ sw;
                short8 Bh = *(const short8*)((const char*)Bs[0] + bb);
                short8 Bl = *(const short8*)((const char*)Bs[1] + bb);
                acc[0][ct] = __builtin_amdgcn_mfma_f32_16x16x32_bf16(A0h, Bh, acc[0][ct], 0, 0, 0);
                acc[0][ct] = __builtin_amdgcn_mfma_f32_16x16x32_bf16(A0h, Bl, acc[0][ct], 0, 0, 0);
                acc[0][ct] = __builtin_amdgcn_mfma_f32_16x16x32_bf16(A0l, Bh, acc[0][ct], 0, 0, 0);
                acc[1][ct] = __builtin_amdgcn_mfma_f32_16x16x32_bf16(A1h, Bh, acc[1][ct], 0, 0, 0);
                acc[1][ct] = __builtin_amdgcn_mfma_f32_16x16x32_bf16(A1h, Bl, acc[1][ct], 0, 0, 0);
                acc[1][ct] = __builtin_amdgcn_mfma_f32_16x16x32_bf16(A1l, Bh, acc[1][ct], 0, 0, 0);
            }
        }
        int orow = (lane >> 4) * 4;
        #pragma unroll
        for (int rt = 0; rt < 2; ++rt) {
            int row = rBase + rt * 16 + orow;
            #pragma unroll
            for (int ct = 0; ct < 8; ++ct) {
                int col = cBase + ct * 16 + lr;
                if (col < 128) {
                    float bias = b0l[col];
                    #pragma unroll
                    for (int j = 0; j < 4; ++j)
                        hl[(size_t)(row + j) * 128 + col] = f2bf(acc[rt][ct][j] + bias);
                } else {
                    int cc = col - 128;
                    #pragma unroll
                    for (int j = 0; j < 4; ++j)
                        agg[(size_t)(row + j) * 128 + cc] = acc[rt][ct][j];
                }
            }
        }
    }
}

// gl(bf16, bias folded) = h2@W1l^T + b1l (cols 0..39); agg2(fp32) = h2@W1r^T
__global__ __launch_bounds__(256) void gemm2_kernel(
        const unsigned short* __restrict__ h2h, const unsigned short* __restrict__ h2l,
        const unsigned short* __restrict__ Wt2h, const unsigned short* __restrict__ Wt2l,
        const float* __restrict__ b1l,
        unsigned short* __restrict__ gl, float* __restrict__ agg2) {
    __shared__ unsigned short Bs[2][80 * 128];    // 40 KB
    int tid = threadIdx.x;
    #pragma unroll
    for (int plane = 0; plane < 2; ++plane) {
        const unsigned short* src = plane ? Wt2l : Wt2h;
        char* dst = (char*)Bs[plane];
        #pragma unroll
        for (int i = 0; i < 5; ++i) {
            int gid = i * 256 + tid;            // 0..1279
            int c = gid >> 4, kc = gid & 15;    // c in [0,80)
            short8 v = *(const short8*)(src + (size_t)c * 128 + kc * 8);
            int byte = (c * 256 + kc * 16) ^ ((c & 7) << 4);
            *(short8*)(dst + byte) = v;
        }
    }
    __syncthreads();

    int wid = tid >> 6, lane = tid & 63;
    int rBase = (blockIdx.x * 4 + wid) * 32;
    if (rBase < N_NODES) {
        int lr = lane & 15;
        int lk = (lane >> 4) * 8;
        int sw = (lr & 7) << 4;
        const unsigned short* a0h = h2h + (size_t)(rBase + lr) * 128 + lk;
        const unsigned short* a0l = h2l + (size_t)(rBase + lr) * 128 + lk;
        const unsigned short* a1h = a0h + 16 * 128;
        const unsigned short* a1l = a0l + 16 * 128;
        f32x4 acc[2][5] = {};
        #pragma unroll
        for (int ks = 0; ks < 4; ++ks) {
            int kb = ks * 32;
            short8 A0h = *(const short8*)(a0h + kb);
            short8 A0l = *(const short8*)(a0l + kb);
            short8 A1h = *(const short8*)(a1h + kb);
            short8 A1l = *(const short8*)(a1l + kb);
            #pragma unroll
            for (int ct = 0; ct < 5; ++ct) {
                int bb = (((ct * 16 + lr) << 8) + (ks << 6) + ((lane >> 4) << 4)) ^ sw;
                short8 Bh = *(const short8*)((const char*)Bs[0] + bb);
                short8 Bl = *(const short8*)((const char*)Bs[1] + bb);
                acc[0][ct] = __builtin_amdgcn_mfma_f32_16x16x32_bf16(A0h, Bh, acc[0][ct], 0, 0, 0);
                acc[0][ct] = __builtin_amdgcn_mfma_f32_16x16x32_bf16(A0h, Bl, acc[0][ct], 0, 0, 0);
                acc[0][ct] = __builtin_amdgcn_mfma_f32_16x16x32_bf16(A0l, Bh, acc[0][ct], 0, 0, 0);
                acc[1][ct] = __builtin_amdgcn_mfma_f32_16x16x32_bf16(A1h, Bh, acc[1][ct], 0, 0, 0);
                acc[1][ct] = __builtin_amdgcn_mfma_f32_16x16x32_bf16(A1h, Bl, acc[1][ct], 0, 0, 0);
                acc[1][ct] = __builtin_amdgcn_mfma_f32_16x16x32_bf16(A1l, Bh, acc[1][ct], 0, 0, 0);
            }
        }
        int orow = (lane >> 4) * 4;
        #pragma unroll
        for (int rt = 0; rt < 2; ++rt) {
            int row = rBase + rt * 16 + orow;
            #pragma unroll
            for (int ct = 0; ct < 5; ++ct) {
                int col = ct * 16 + lr;   // 0..79
                if (col < 40) {
                    float bias = b1l[col];
                    #pragma unroll
                    for (int j = 0; j < 4; ++j)
                        gl[(size_t)(row + j) * 40 + col] = f2bf(acc[rt][ct][j] + bias);
                } else {
                    int cc = col - 40;
                    #pragma unroll
                    for (int j = 0; j < 4; ++j)
                        agg2[(size_t)(row + j) * 40 + cc] = acc[rt][ct][j];
                }
            }
        }
    }
}

// gather bf16 messages + fused l2norm+LN+relu -> split-bf16 h2; wave per node
__global__ __launch_bounds__(256) void gather1_kernel(const int* __restrict__ rowStart,
        const unsigned int* __restrict__ sPk, const unsigned short* __restrict__ hl,
        const float* __restrict__ agg,
        const float* __restrict__ g, const float* __restrict__ b,
        unsigned short* __restrict__ h2h, unsigned short* __restrict__ h2l) {
    int row = blockIdx.x * 4 + (threadIdx.x >> 6);
    int lane = threadIdx.x & 63;
    int beg = rowStart[row], end = rowStart[row + 1];
    float2 acc = ((const float2*)(agg + (size_t)row * 128))[lane];  // root term
    int e = beg;
    for (; e + 4 <= end; e += 4) {
        unsigned int p0 = sPk[e], p1 = sPk[e + 1], p2 = sPk[e + 2], p3 = sPk[e + 3];
        ushort2 u0 = ((const ushort2*)(hl + (size_t)(p0 & 0xFFFF) * 128))[lane];
        ushort2 u1 = ((const ushort2*)(hl + (size_t)(p1 & 0xFFFF) * 128))[lane];
        ushort2 u2 = ((const ushort2*)(hl + (size_t)(p2 & 0xFFFF) * 128))[lane];
        ushort2 u3 = ((const ushort2*)(hl + (size_t)(p3 & 0xFFFF) * 128))[lane];
        float w0 = bf2f((unsigned short)(p0 >> 16));
        float w1 = bf2f((unsigned short)(p1 >> 16));
        float w2 = bf2f((unsigned short)(p2 >> 16));
        float w3 = bf2f((unsigned short)(p3 >> 16));
        acc.x = fmaf(bf2f(u0.x), w0, acc.x); acc.y = fmaf(bf2f(u0.y), w0, acc.y);
        acc.x = fmaf(bf2f(u1.x), w1, acc.x); acc.y = fmaf(bf2f(u1.y), w1, acc.y);
        acc.x = fmaf(bf2f(u2.x), w2, acc.x); acc.y = fmaf(bf2f(u2.y), w2, acc.y);
        acc.x = fmaf(bf2f(u3.x), w3, acc.x); acc.y = fmaf(bf2f(u3.y), w3, acc.y);
    }
    for (; e < end; ++e) {
        unsigned int p = sPk[e];
        ushort2 u = ((const ushort2*)(hl + (size_t)(p & 0xFFFF) * 128))[lane];
        float w = bf2f((unsigned short)(p >> 16));
        acc.x = fmaf(bf2f(u.x), w, acc.x);
        acc.y = fmaf(bf2f(u.y), w, acc.y);
    }
    float nrm = sqrtf(wave_sum(acc.x * acc.x + acc.y * acc.y));
    float inv = 1.0f / fmaxf(nrm, 1e-12f);
    float vx = acc.x * inv, vy = acc.y * inv;
    float mu = wave_sum(vx + vy) * (1.0f / 128.0f);
    float dx = vx - mu, dy = vy - mu;
    float var = wave_sum(dx * dx + dy * dy) * (1.0f / 128.0f);
    float rs = rsqrtf(var + 1e-5f);
    float2 gv = ((const float2*)g)[lane];
    float2 bv = ((const float2*)b)[lane];
    float ox = fmaxf(dx * rs * gv.x + bv.x, 0.0f);
    float oy = fmaxf(dy * rs * gv.y + bv.y, 0.0f);
    ushort2 hv, lv;
    hv.x = f2bf(ox); hv.y = f2bf(oy);
    lv.x = f2bf(ox - bf2f(hv.x)); lv.y = f2bf(oy - bf2f(hv.y));
    ((ushort2*)(h2h + (size_t)row * 128))[lane] = hv;
    ((ushort2*)(h2l + (size_t)row * 128))[lane] = lv;
}

// gather bf16 messages + fused l2norm + log_softmax; wave per node, lanes 0..39
__global__ __launch_bounds__(256) void gather2_kernel(const int* __restrict__ rowStart,
        const unsigned int* __restrict__ sPk, const unsigned short* __restrict__ gl,
        const float* __restrict__ agg2, float* __restrict__ out) {
    int row = blockIdx.x * 4 + (threadIdx.x >> 6);
    int lane = threadIdx.x & 63;
    bool act = lane < 40;
    int beg = rowStart[row], end = rowStart[row + 1];
    float acc = act ? agg2[(size_t)row * 40 + lane] : 0.0f;  // root term
    int e = beg;
    for (; e + 2 <= end; e += 2) {
        unsigned int p0 = sPk[e], p1 = sPk[e + 1];
        if (act) {
            float v0 = bf2f(gl[(size_t)(p0 & 0xFFFF) * 40 + lane]);
            float v1 = bf2f(gl[(size_t)(p1 & 0xFFFF) * 40 + lane]);
            acc = fmaf(v0, bf2f((unsigned short)(p0 >> 16)), acc);
            acc = fmaf(v1, bf2f((unsigned short)(p1 >> 16)), acc);
        }
    }
    if (e < end) {
        unsigned int p = sPk[e];
        if (act) {
            float v = bf2f(gl[(size_t)(p & 0xFFFF) * 40 + lane]);
            acc = fmaf(v, bf2f((unsigned short)(p >> 16)), acc);
        }
    }
    float nrm = sqrtf(wave_sum(act ? acc * acc : 0.0f));
    float o = acc / fmaxf(nrm, 1e-12f);
    float m = wave_max(act ? o : -INFINITY);
    float s = wave_sum(act ? expf(o - m) : 0.0f);
    float ls = logf(s);
    if (act) out[(size_t)row * 40 + lane] = o - m - ls;
}

extern "C" void kernel_launch(void* const* d_in, const int* in_sizes, int n_in,
                              void* d_out, int out_size, void* d_ws, size_t ws_size,
                              hipStream_t stream) {
    const float* x    = (const float*)d_in[0];
    const int*   ei   = (const int*)d_in[1];
    const float* ew   = (const float*)d_in[2];
    const float* ln0g = (const float*)d_in[3];
    const float* ln0b = (const float*)d_in[4];
    const float* W0l  = (const float*)d_in[5];
    const float* b0l  = (const float*)d_in[6];
    const float* W0r  = (const float*)d_in[7];
    const float* ln1g = (const float*)d_in[8];
    const float* ln1b = (const float*)d_in[9];
    const float* W1l  = (const float*)d_in[10];
    const float* b1l  = (const float*)d_in[11];
    const float* W1r  = (const float*)d_in[12];
    float* out = (float*)d_out;

    const size_t NBUF = (size_t)N_NODES * 128;  // 5.12M elems
    char* p = (char*)d_ws;
    auto alloc = [&](size_t bytes) { char* r = p; p += (bytes + 255) & ~(size_t)255; return r; };
    float*          agg  = (float*)alloc(NBUF * 4);          // agg / agg2 (fp32)
    unsigned short* hl   = (unsigned short*)alloc(NBUF * 2); // hl / gl (bf16)
    unsigned short* h0h  = (unsigned short*)alloc(NBUF * 2); // h0 hi / h2 hi
    unsigned short* h0l  = (unsigned short*)alloc(NBUF * 2); // h0 lo / h2 lo
    unsigned short* Wt1h = (unsigned short*)alloc(256 * 128 * 2);
    unsigned short* Wt1l = (unsigned short*)alloc(256 * 128 * 2);
    unsigned short* Wt2h = (unsigned short*)alloc(80 * 128 * 2);
    unsigned short* Wt2l = (unsigned short*)alloc(80 * 128 * 2);
    unsigned int*   sPk  = (unsigned int*)alloc((size_t)N_EDGES * 4);
    int*            deg  = (int*)alloc(N_NODES * 4);
    int*       rowStart  = (int*)alloc((N_NODES + 1) * 4);
    int*         cursor  = (int*)alloc(N_NODES * 4);
    int*      blockSums  = (int*)alloc(256 * 4);
    int*      blockOffs  = (int*)alloc(256 * 4);
    unsigned short* gl   = hl;    // hl dead after gather1
    float*        agg2   = agg;   // agg dead after gather1

    // 1. zero deg (must precede fused histogram)
    zero_deg<<<SCAN_BLOCKS, 256, 0, stream>>>(deg);
    // 2. fused LN0 + weight prep + deg histogram (interleaved blocks for overlap)
    comboDeg_kernel<<<12712, 256, 0, stream>>>(x, ln0g, ln0b, h0h, h0l,
            W0l, W0r, W1l, W1r, Wt1h, Wt1l, Wt2h, Wt2l, deg, ei);
    // 3. CSR scans
    scanA<<<SCAN_BLOCKS, 256, 0, stream>>>(deg, rowStart, blockSums);
    scanB<<<1, 256, 0, stream>>>(blockSums, blockOffs);
    scanC<<<SCAN_BLOCKS, 256, 0, stream>>>(blockOffs, rowStart, cursor);
    // 4. bucket-fill dst-sorted edges
    fill_kernel<<<FILLB, 256, 0, stream>>>(ei, ew, cursor, sPk);
    // 5-8. pipeline
    gemm1_kernel<<<dim3(313, 2), 256, 0, stream>>>(h0h, h0l, Wt1h, Wt1l, b0l, hl, agg);
    gather1_kernel<<<N_NODES / 4, 256, 0, stream>>>(rowStart, sPk, hl, agg,
                                                    ln1g, ln1b, h0h, h0l);
    gemm2_kernel<<<313, 256, 0, stream>>>(h0h, h0l, Wt2h, Wt2l, b1l, gl, agg2);
    gather2_kernel<<<N_NODES / 4, 256, 0, stream>>>(rowStart, sPk, gl, agg2, out);
}

// Round 6
// 168.013 us; speedup vs baseline: 1.3043x; 1.0969x over previous
//
#include <hip/hip_runtime.h>
#include <math.h>

#define N_NODES 40000
#define N_EDGES 640000
#define SCAN_BLOCKS ((N_NODES + 255) / 256)   // 157
#define FILLB (N_EDGES / 256)                 // 2500
#define FGRP 8                                // fill dst-range groups (XCD-affine)
#define FRANGE (N_NODES / FGRP)               // 5000 dst per group

typedef __attribute__((ext_vector_type(8))) short short8;   // 8 bf16 (A/B frag)
typedef __attribute__((ext_vector_type(4))) float f32x4;    // C/D frag

__device__ __forceinline__ unsigned short f2bf(float f) {
    union { float f; unsigned u; } v; v.f = f;
    unsigned r = (v.u + 0x7FFFu + ((v.u >> 16) & 1u)) >> 16;  // RNE
    return (unsigned short)r;
}
__device__ __forceinline__ float bf2f(unsigned short h) {
    union { unsigned u; float f; } v; v.u = ((unsigned)h) << 16;
    return v.f;
}

__device__ __forceinline__ float wave_sum(float v) {
    #pragma unroll
    for (int m = 1; m < 64; m <<= 1) v += __shfl_xor(v, m, 64);
    return v;
}
__device__ __forceinline__ float wave_max(float v) {
    #pragma unroll
    for (int m = 1; m < 64; m <<= 1) v = fmaxf(v, __shfl_xor(v, m, 64));
    return v;
}

__global__ __launch_bounds__(256) void zero_deg(int* __restrict__ deg) {
    int i = blockIdx.x * 256 + threadIdx.x;
    if (i < N_NODES) deg[i] = 0;
}

// Interleaved fusion (every 5th block = deg histogram; rest = LN0 / weight prep)
__global__ __launch_bounds__(256) void comboDeg_kernel(const float* __restrict__ x,
        const float* __restrict__ g, const float* __restrict__ b,
        unsigned short* __restrict__ h0h, unsigned short* __restrict__ h0l,
        const float* __restrict__ W0l, const float* __restrict__ W0r,
        const float* __restrict__ W1l, const float* __restrict__ W1r,
        unsigned short* __restrict__ Wt1h, unsigned short* __restrict__ Wt1l,
        unsigned short* __restrict__ Wt2h, unsigned short* __restrict__ Wt2l,
        int* __restrict__ deg, const int* __restrict__ ei) {
    int bid = blockIdx.x;
    if ((bid % 5) == 4) {
        int db = bid / 5;
        if (db < FILLB) {
            int e = db * 256 + threadIdx.x;
            atomicAdd(&deg[ei[N_EDGES + e]], 1);
        }
        return;
    }
    int cb = bid - bid / 5;
    if (cb < 10000) {
        int row = cb * 4 + (threadIdx.x >> 6);
        int lane = threadIdx.x & 63;
        float2 v = ((const float2*)(x + (size_t)row * 128))[lane];
        float mu = wave_sum(v.x + v.y) * (1.0f / 128.0f);
        float dx = v.x - mu, dy = v.y - mu;
        float var = wave_sum(dx * dx + dy * dy) * (1.0f / 128.0f);
        float rs = rsqrtf(var + 1e-5f);
        float2 gv = ((const float2*)g)[lane];
        float2 bv = ((const float2*)b)[lane];
        float ox = dx * rs * gv.x + bv.x;
        float oy = dy * rs * gv.y + bv.y;
        ushort2 hv, lv;
        hv.x = f2bf(ox); hv.y = f2bf(oy);
        lv.x = f2bf(ox - bf2f(hv.x)); lv.y = f2bf(oy - bf2f(hv.y));
        ((ushort2*)(h0h + (size_t)row * 128))[lane] = hv;
        ((ushort2*)(h0l + (size_t)row * 128))[lane] = lv;
    } else if (cb < 10168) {
        int i = (cb - 10000) * 256 + threadIdx.x;   // 0..43007
        float w; unsigned short *ph, *pl; int idx;
        if (i < 256 * 128) {
            int c = i >> 7, k = i & 127;
            w = (c < 128) ? W0l[c * 128 + k] : W0r[(c - 128) * 128 + k];
            ph = Wt1h; pl = Wt1l; idx = i;
        } else {
            int j = i - 256 * 128;
            int c = j >> 7, k = j & 127;
            w = (c < 40) ? W1l[c * 128 + k] : W1r[(c - 40) * 128 + k];
            ph = Wt2h; pl = Wt2l; idx = j;
        }
        unsigned short hi = f2bf(w);
        ph[idx] = hi;
        pl[idx] = f2bf(w - bf2f(hi));
    }
}

// ---------------- CSR scans ----------------

__global__ __launch_bounds__(256) void scanA(const int* __restrict__ deg,
        int* __restrict__ rowStart, int* __restrict__ blockSums) {
    int i = blockIdx.x * 256 + threadIdx.x;
    int lane = threadIdx.x & 63, wid = threadIdx.x >> 6;
    int v = (i < N_NODES) ? deg[i] : 0;
    int s = v;
    #pragma unroll
    for (int m = 1; m < 64; m <<= 1) {
        int u = __shfl_up(s, m, 64);
        if (lane >= m) s += u;
    }
    __shared__ int wsum[4];
    if (lane == 63) wsum[wid] = s;
    __syncthreads();
    int off = 0;
    for (int w = 0; w < wid; ++w) off += wsum[w];
    if (i < N_NODES) rowStart[i] = off + s - v;
    if (threadIdx.x == 255) blockSums[blockIdx.x] = off + s;
}

__global__ __launch_bounds__(256) void scanB(const int* __restrict__ blockSums,
        int* __restrict__ blockOffs) {
    int t = threadIdx.x;
    int lane = t & 63, wid = t >> 6;
    int v = (t < SCAN_BLOCKS) ? blockSums[t] : 0;
    int s = v;
    #pragma unroll
    for (int m = 1; m < 64; m <<= 1) {
        int u = __shfl_up(s, m, 64);
        if (lane >= m) s += u;
    }
    __shared__ int wsum[4];
    if (lane == 63) wsum[wid] = s;
    __syncthreads();
    int off = 0;
    for (int w = 0; w < wid; ++w) off += wsum[w];
    blockOffs[t] = off + s - v;
}

__global__ __launch_bounds__(256) void scanC(const int* __restrict__ blockOffs,
        int* __restrict__ rowStart, int* __restrict__ cursor) {
    int i = blockIdx.x * 256 + threadIdx.x;
    if (i < N_NODES) {
        int v = rowStart[i] + blockOffs[blockIdx.x];
        rowStart[i] = v;
        cursor[i] = v;
    }
    if (i == 0) rowStart[N_NODES] = N_EDGES;
}

// bucket-fill packed edges, dst-range partitioned for XCD-local writes.
// group g = blockIdx&7 handles dst in [g*5000,(g+1)*5000): sPk region is
// contiguous (dst-sorted), so each region's lines are written by one XCD only.
__global__ __launch_bounds__(256) void fill_kernel(const int* __restrict__ ei,
        const float* __restrict__ ew, int* __restrict__ cursor,
        unsigned int* __restrict__ sPk) {
    int g = blockIdx.x & (FGRP - 1);
    int c = blockIdx.x >> 3;              // chunk 0..2499
    int e = c * 256 + threadIdx.x;
    int d = ei[N_EDGES + e];
    int lo = g * FRANGE;
    if (d >= lo && d < lo + FRANGE) {
        unsigned int pk = (unsigned int)ei[e] | ((unsigned int)f2bf(ew[e]) << 16);
        int idx = atomicAdd(&cursor[d], 1);
        sPk[idx] = pk;
    }
}

// ---------------- MFMA GEMMs, B staged in LDS (XOR-swizzled) ----------------

// hl(bf16, bias folded) = h0@W0l^T + b0l (cols 0..127); agg(fp32) = h0@W0r^T
__global__ __launch_bounds__(256) void gemm1_kernel(
        const unsigned short* __restrict__ h0h, const unsigned short* __restrict__ h0l,
        const unsigned short* __restrict__ Wt1h, const unsigned short* __restrict__ Wt1l,
        const float* __restrict__ b0l,
        unsigned short* __restrict__ hl, float* __restrict__ agg) {
    __shared__ unsigned short Bs[2][128 * 128];   // 64 KB
    int tid = threadIdx.x;
    int cBase = blockIdx.y * 128;
    #pragma unroll
    for (int plane = 0; plane < 2; ++plane) {
        const unsigned short* src = plane ? Wt1l : Wt1h;
        char* dst = (char*)Bs[plane];
        #pragma unroll
        for (int i = 0; i < 8; ++i) {
            int gid = i * 256 + tid;
            int c = gid >> 4, kc = gid & 15;
            short8 v = *(const short8*)(src + (size_t)(cBase + c) * 128 + kc * 8);
            int byte = (c * 256 + kc * 16) ^ ((c & 7) << 4);
            *(short8*)(dst + byte) = v;
        }
    }
    __syncthreads();

    int wid = tid >> 6, lane = tid & 63;
    int rBase = (blockIdx.x * 4 + wid) * 32;
    if (rBase < N_NODES) {
        int lr = lane & 15;
        int lk = (lane >> 4) * 8;
        int sw = (lr & 7) << 4;
        const unsigned short* a0h = h0h + (size_t)(rBase + lr) * 128 + lk;
        const unsigned short* a0l = h0l + (size_t)(rBase + lr) * 128 + lk;
        const unsigned short* a1h = a0h + 16 * 128;
        const unsigned short* a1l = a0l + 16 * 128;
        f32x4 acc[2][8] = {};
        #pragma unroll
        for (int ks = 0; ks < 4; ++ks) {
            int kb = ks * 32;
            short8 A0h = *(const short8*)(a0h + kb);
            short8 A0l = *(const short8*)(a0l + kb);
            short8 A1h = *(const short8*)(a1h + kb);
            short8 A1l = *(const short8*)(a1l + kb);
            #pragma unroll
            for (int ct = 0; ct < 8; ++ct) {
                int bb = (((ct * 16 + lr) << 8) + (ks << 6) + ((lane >> 4) << 4)) ^ sw;
                short8 Bh = *(const short8*)((const char*)Bs[0] + bb);
                short8 Bl = *(const short8*)((const char*)Bs[1] + bb);
                acc[0][ct] = __builtin_amdgcn_mfma_f32_16x16x32_bf16(A0h, Bh, acc[0][ct], 0, 0, 0);
                acc[0][ct] = __builtin_amdgcn_mfma_f32_16x16x32_bf16(A0h, Bl, acc[0][ct], 0, 0, 0);
                acc[0][ct] = __builtin_amdgcn_mfma_f32_16x16x32_bf16(A0l, Bh, acc[0][ct], 0, 0, 0);
                acc[1][ct] = __builtin_amdgcn_mfma_f32_16x16x32_bf16(A1h, Bh, acc[1][ct], 0, 0, 0);
                acc[1][ct] = __builtin_amdgcn_mfma_f32_16x16x32_bf16(A1h, Bl, acc[1][ct], 0, 0, 0);
                acc[1][ct] = __builtin_amdgcn_mfma_f32_16x16x32_bf16(A1l, Bh, acc[1][ct], 0, 0, 0);
            }
        }
        int orow = (lane >> 4) * 4;
        #pragma unroll
        for (int rt = 0; rt < 2; ++rt) {
            int row = rBase + rt * 16 + orow;
            #pragma unroll
            for (int ct = 0; ct < 8; ++ct) {
                int col = cBase + ct * 16 + lr;
                if (col < 128) {
                    float bias = b0l[col];
                    #pragma unroll
                    for (int j = 0; j < 4; ++j)
                        hl[(size_t)(row + j) * 128 + col] = f2bf(acc[rt][ct][j] + bias);
                } else {
                    int cc = col - 128;
                    #pragma unroll
                    for (int j = 0; j < 4; ++j)
                        agg[(size_t)(row + j) * 128 + cc] = acc[rt][ct][j];
                }
            }
        }
    }
}

// gl(bf16, bias folded) = h2@W1l^T + b1l (cols 0..39); agg2(fp32) = h2@W1r^T
__global__ __launch_bounds__(256) void gemm2_kernel(
        const unsigned short* __restrict__ h2h, const unsigned short* __restrict__ h2l,
        const unsigned short* __restrict__ Wt2h, const unsigned short* __restrict__ Wt2l,
        const float* __restrict__ b1l,
        unsigned short* __restrict__ gl, float* __restrict__ agg2) {
    __shared__ unsigned short Bs[2][80 * 128];    // 40 KB
    int tid = threadIdx.x;
    #pragma unroll
    for (int plane = 0; plane < 2; ++plane) {
        const unsigned short* src = plane ? Wt2l : Wt2h;
        char* dst = (char*)Bs[plane];
        #pragma unroll
        for (int i = 0; i < 5; ++i) {
            int gid = i * 256 + tid;
            int c = gid >> 4, kc = gid & 15;
            short8 v = *(const short8*)(src + (size_t)c * 128 + kc * 8);
            int byte = (c * 256 + kc * 16) ^ ((c & 7) << 4);
            *(short8*)(dst + byte) = v;
        }
    }
    __syncthreads();

    int wid = tid >> 6, lane = tid & 63;
    int rBase = (blockIdx.x * 4 + wid) * 32;
    if (rBase < N_NODES) {
        int lr = lane & 15;
        int lk = (lane >> 4) * 8;
        int sw = (lr & 7) << 4;
        const unsigned short* a0h = h2h + (size_t)(rBase + lr) * 128 + lk;
        const unsigned short* a0l = h2l + (size_t)(rBase + lr) * 128 + lk;
        const unsigned short* a1h = a0h + 16 * 128;
        const unsigned short* a1l = a0l + 16 * 128;
        f32x4 acc[2][5] = {};
        #pragma unroll
        for (int ks = 0; ks < 4; ++ks) {
            int kb = ks * 32;
            short8 A0h = *(const short8*)(a0h + kb);
            short8 A0l = *(const short8*)(a0l + kb);
            short8 A1h = *(const short8*)(a1h + kb);
            short8 A1l = *(const short8*)(a1l + kb);
            #pragma unroll
            for (int ct = 0; ct < 5; ++ct) {
                int bb = (((ct * 16 + lr) << 8) + (ks << 6) + ((lane >> 4) << 4)) ^ sw;
                short8 Bh = *(const short8*)((const char*)Bs[0] + bb);
                short8 Bl = *(const short8*)((const char*)Bs[1] + bb);
                acc[0][ct] = __builtin_amdgcn_mfma_f32_16x16x32_bf16(A0h, Bh, acc[0][ct], 0, 0, 0);
                acc[0][ct] = __builtin_amdgcn_mfma_f32_16x16x32_bf16(A0h, Bl, acc[0][ct], 0, 0, 0);
                acc[0][ct] = __builtin_amdgcn_mfma_f32_16x16x32_bf16(A0l, Bh, acc[0][ct], 0, 0, 0);
                acc[1][ct] = __builtin_amdgcn_mfma_f32_16x16x32_bf16(A1h, Bh, acc[1][ct], 0, 0, 0);
                acc[1][ct] = __builtin_amdgcn_mfma_f32_16x16x32_bf16(A1h, Bl, acc[1][ct], 0, 0, 0);
                acc[1][ct] = __builtin_amdgcn_mfma_f32_16x16x32_bf16(A1l, Bh, acc[1][ct], 0, 0, 0);
            }
        }
        int orow = (lane >> 4) * 4;
        #pragma unroll
        for (int rt = 0; rt < 2; ++rt) {
            int row = rBase + rt * 16 + orow;
            #pragma unroll
            for (int ct = 0; ct < 5; ++ct) {
                int col = ct * 16 + lr;   // 0..79
                if (col < 40) {
                    float bias = b1l[col];
                    #pragma unroll
                    for (int j = 0; j < 4; ++j)
                        gl[(size_t)(row + j) * 40 + col] = f2bf(acc[rt][ct][j] + bias);
                } else {
                    int cc = col - 40;
                    #pragma unroll
                    for (int j = 0; j < 4; ++j)
                        agg2[(size_t)(row + j) * 40 + cc] = acc[rt][ct][j];
                }
            }
        }
    }
}

// gather bf16 messages + fused l2norm+LN+relu -> split-bf16 h2; wave per node
__global__ __launch_bounds__(256) void gather1_kernel(const int* __restrict__ rowStart,
        const unsigned int* __restrict__ sPk, const unsigned short* __restrict__ hl,
        const float* __restrict__ agg,
        const float* __restrict__ g, const float* __restrict__ b,
        unsigned short* __restrict__ h2h, unsigned short* __restrict__ h2l) {
    int row = blockIdx.x * 4 + (threadIdx.x >> 6);
    int lane = threadIdx.x & 63;
    int beg = rowStart[row], end = rowStart[row + 1];
    float2 acc = ((const float2*)(agg + (size_t)row * 128))[lane];  // root term
    int e = beg;
    for (; e + 4 <= end; e += 4) {
        unsigned int p0 = sPk[e], p1 = sPk[e + 1], p2 = sPk[e + 2], p3 = sPk[e + 3];
        ushort2 u0 = ((const ushort2*)(hl + (size_t)(p0 & 0xFFFF) * 128))[lane];
        ushort2 u1 = ((const ushort2*)(hl + (size_t)(p1 & 0xFFFF) * 128))[lane];
        ushort2 u2 = ((const ushort2*)(hl + (size_t)(p2 & 0xFFFF) * 128))[lane];
        ushort2 u3 = ((const ushort2*)(hl + (size_t)(p3 & 0xFFFF) * 128))[lane];
        float w0 = bf2f((unsigned short)(p0 >> 16));
        float w1 = bf2f((unsigned short)(p1 >> 16));
        float w2 = bf2f((unsigned short)(p2 >> 16));
        float w3 = bf2f((unsigned short)(p3 >> 16));
        acc.x = fmaf(bf2f(u0.x), w0, acc.x); acc.y = fmaf(bf2f(u0.y), w0, acc.y);
        acc.x = fmaf(bf2f(u1.x), w1, acc.x); acc.y = fmaf(bf2f(u1.y), w1, acc.y);
        acc.x = fmaf(bf2f(u2.x), w2, acc.x); acc.y = fmaf(bf2f(u2.y), w2, acc.y);
        acc.x = fmaf(bf2f(u3.x), w3, acc.x); acc.y = fmaf(bf2f(u3.y), w3, acc.y);
    }
    for (; e < end; ++e) {
        unsigned int p = sPk[e];
        ushort2 u = ((const ushort2*)(hl + (size_t)(p & 0xFFFF) * 128))[lane];
        float w = bf2f((unsigned short)(p >> 16));
        acc.x = fmaf(bf2f(u.x), w, acc.x);
        acc.y = fmaf(bf2f(u.y), w, acc.y);
    }
    float nrm = sqrtf(wave_sum(acc.x * acc.x + acc.y * acc.y));
    float inv = 1.0f / fmaxf(nrm, 1e-12f);
    float vx = acc.x * inv, vy = acc.y * inv;
    float mu = wave_sum(vx + vy) * (1.0f / 128.0f);
    float dx = vx - mu, dy = vy - mu;
    float var = wave_sum(dx * dx + dy * dy) * (1.0f / 128.0f);
    float rs = rsqrtf(var + 1e-5f);
    float2 gv = ((const float2*)g)[lane];
    float2 bv = ((const float2*)b)[lane];
    float ox = fmaxf(dx * rs * gv.x + bv.x, 0.0f);
    float oy = fmaxf(dy * rs * gv.y + bv.y, 0.0f);
    ushort2 hv, lv;
    hv.x = f2bf(ox); hv.y = f2bf(oy);
    lv.x = f2bf(ox - bf2f(hv.x)); lv.y = f2bf(oy - bf2f(hv.y));
    ((ushort2*)(h2h + (size_t)row * 128))[lane] = hv;
    ((ushort2*)(h2l + (size_t)row * 128))[lane] = lv;
}

// gather bf16 messages + fused l2norm + log_softmax; 4-edge unroll
__global__ __launch_bounds__(256) void gather2_kernel(const int* __restrict__ rowStart,
        const unsigned int* __restrict__ sPk, const unsigned short* __restrict__ gl,
        const float* __restrict__ agg2, float* __restrict__ out) {
    int row = blockIdx.x * 4 + (threadIdx.x >> 6);
    int lane = threadIdx.x & 63;
    bool act = lane < 40;
    int beg = rowStart[row], end = rowStart[row + 1];
    float acc = act ? agg2[(size_t)row * 40 + lane] : 0.0f;  // root term
    int e = beg;
    for (; e + 4 <= end; e += 4) {
        unsigned int p0 = sPk[e], p1 = sPk[e + 1], p2 = sPk[e + 2], p3 = sPk[e + 3];
        if (act) {
            float v0 = bf2f(gl[(size_t)(p0 & 0xFFFF) * 40 + lane]);
            float v1 = bf2f(gl[(size_t)(p1 & 0xFFFF) * 40 + lane]);
            float v2 = bf2f(gl[(size_t)(p2 & 0xFFFF) * 40 + lane]);
            float v3 = bf2f(gl[(size_t)(p3 & 0xFFFF) * 40 + lane]);
            acc = fmaf(v0, bf2f((unsigned short)(p0 >> 16)), acc);
            acc = fmaf(v1, bf2f((unsigned short)(p1 >> 16)), acc);
            acc = fmaf(v2, bf2f((unsigned short)(p2 >> 16)), acc);
            acc = fmaf(v3, bf2f((unsigned short)(p3 >> 16)), acc);
        }
    }
    for (; e < end; ++e) {
        unsigned int p = sPk[e];
        if (act) {
            float v = bf2f(gl[(size_t)(p & 0xFFFF) * 40 + lane]);
            acc = fmaf(v, bf2f((unsigned short)(p >> 16)), acc);
        }
    }
    float nrm = sqrtf(wave_sum(act ? acc * acc : 0.0f));
    float o = acc / fmaxf(nrm, 1e-12f);
    float m = wave_max(act ? o : -INFINITY);
    float s = wave_sum(act ? expf(o - m) : 0.0f);
    float ls = logf(s);
    if (act) out[(size_t)row * 40 + lane] = o - m - ls;
}

extern "C" void kernel_launch(void* const* d_in, const int* in_sizes, int n_in,
                              void* d_out, int out_size, void* d_ws, size_t ws_size,
                              hipStream_t stream) {
    const float* x    = (const float*)d_in[0];
    const int*   ei   = (const int*)d_in[1];
    const float* ew   = (const float*)d_in[2];
    const float* ln0g = (const float*)d_in[3];
    const float* ln0b = (const float*)d_in[4];
    const float* W0l  = (const float*)d_in[5];
    const float* b0l  = (const float*)d_in[6];
    const float* W0r  = (const float*)d_in[7];
    const float* ln1g = (const float*)d_in[8];
    const float* ln1b = (const float*)d_in[9];
    const float* W1l  = (const float*)d_in[10];
    const float* b1l  = (const float*)d_in[11];
    const float* W1r  = (const float*)d_in[12];
    float* out = (float*)d_out;

    const size_t NBUF = (size_t)N_NODES * 128;  // 5.12M elems
    char* p = (char*)d_ws;
    auto alloc = [&](size_t bytes) { char* r = p; p += (bytes + 255) & ~(size_t)255; return r; };
    float*          agg  = (float*)alloc(NBUF * 4);          // agg / agg2 (fp32)
    unsigned short* hl   = (unsigned short*)alloc(NBUF * 2); // hl / gl (bf16)
    unsigned short* h0h  = (unsigned short*)alloc(NBUF * 2); // h0 hi / h2 hi
    unsigned short* h0l  = (unsigned short*)alloc(NBUF * 2); // h0 lo / h2 lo
    unsigned short* Wt1h = (unsigned short*)alloc(256 * 128 * 2);
    unsigned short* Wt1l = (unsigned short*)alloc(256 * 128 * 2);
    unsigned short* Wt2h = (unsigned short*)alloc(80 * 128 * 2);
    unsigned short* Wt2l = (unsigned short*)alloc(80 * 128 * 2);
    unsigned int*   sPk  = (unsigned int*)alloc((size_t)N_EDGES * 4);
    int*            deg  = (int*)alloc(N_NODES * 4);
    int*       rowStart  = (int*)alloc((N_NODES + 1) * 4);
    int*         cursor  = (int*)alloc(N_NODES * 4);
    int*      blockSums  = (int*)alloc(256 * 4);
    int*      blockOffs  = (int*)alloc(256 * 4);
    unsigned short* gl   = hl;    // hl dead after gather1
    float*        agg2   = agg;   // agg dead after gather1

    // 1. zero deg
    zero_deg<<<SCAN_BLOCKS, 256, 0, stream>>>(deg);
    // 2. fused LN0 + weight prep + deg histogram
    comboDeg_kernel<<<12712, 256, 0, stream>>>(x, ln0g, ln0b, h0h, h0l,
            W0l, W0r, W1l, W1r, Wt1h, Wt1l, Wt2h, Wt2l, deg, ei);
    // 3. CSR scans
    scanA<<<SCAN_BLOCKS, 256, 0, stream>>>(deg, rowStart, blockSums);
    scanB<<<1, 256, 0, stream>>>(blockSums, blockOffs);
    scanC<<<SCAN_BLOCKS, 256, 0, stream>>>(blockOffs, rowStart, cursor);
    // 4. bucket-fill, dst-range partitioned (XCD-local writes)
    fill_kernel<<<FILLB * FGRP, 256, 0, stream>>>(ei, ew, cursor, sPk);
    // 5-8. pipeline
    gemm1_kernel<<<dim3(313, 2), 256, 0, stream>>>(h0h, h0l, Wt1h, Wt1l, b0l, hl, agg);
    gather1_kernel<<<N_NODES / 4, 256, 0, stream>>>(rowStart, sPk, hl, agg,
                                                    ln1g, ln1b, h0h, h0l);
    gemm2_kernel<<<313, 256, 0, stream>>>(h0h, h0l, Wt2h, Wt2l, b1l, gl, agg2);
    gather2_kernel<<<N_NODES / 4, 256, 0, stream>>>(rowStart, sPk, gl, agg2, out);
}

// Round 7
// 131.983 us; speedup vs baseline: 1.6603x; 1.2730x over previous
//
#include <hip/hip_runtime.h>
#include <math.h>

#define N_NODES 40000
#define N_EDGES 640000
#define BCAP 64                     // bucket capacity per dst (P(deg>64) ~ 4e-18)
#define FGRP 8                      // fill dst-range groups (XCD-affine)
#define FRANGE (N_NODES / FGRP)     // 5000 dst per group
#define NSG 1271                    // supergroups: 1271*8 = 10168 combo blocks exactly

typedef __attribute__((ext_vector_type(8))) short short8;   // 8 bf16 (A/B frag)
typedef __attribute__((ext_vector_type(4))) float f32x4;    // C/D frag

__device__ __forceinline__ unsigned short f2bf(float f) {
    union { float f; unsigned u; } v; v.f = f;
    unsigned r = (v.u + 0x7FFFu + ((v.u >> 16) & 1u)) >> 16;  // RNE
    return (unsigned short)r;
}
__device__ __forceinline__ float bf2f(unsigned short h) {
    union { unsigned u; float f; } v; v.u = ((unsigned)h) << 16;
    return v.f;
}

__device__ __forceinline__ float wave_sum(float v) {
    #pragma unroll
    for (int m = 1; m < 64; m <<= 1) v += __shfl_xor(v, m, 64);
    return v;
}
__device__ __forceinline__ float wave_max(float v) {
    #pragma unroll
    for (int m = 1; m < 64; m <<= 1) v = fmaxf(v, __shfl_xor(v, m, 64));
    return v;
}

// Supergroup-24 interleaved fusion: per 24 consecutive blocks,
//   phase 0..7  -> combo work (LN0 rows, then weight prep)      [8 * 1271 = 10168]
//   phase 8..23 -> bucket-fill, dst-group g = bid&7 (XCD-affine) [2 chunks/group/sg]
// fill is independent of combo (only needs cnt pre-zeroed), so the two phases
// genuinely overlap across the grid (R5 interleave lesson; NOT R4 range-split).
__global__ __launch_bounds__(256) void comboFill_kernel(const float* __restrict__ x,
        const float* __restrict__ g, const float* __restrict__ b,
        unsigned short* __restrict__ h0h, unsigned short* __restrict__ h0l,
        const float* __restrict__ W0l, const float* __restrict__ W0r,
        const float* __restrict__ W1l, const float* __restrict__ W1r,
        unsigned short* __restrict__ Wt1h, unsigned short* __restrict__ Wt1l,
        unsigned short* __restrict__ Wt2h, unsigned short* __restrict__ Wt2l,
        const int* __restrict__ ei, const float* __restrict__ ew,
        int* __restrict__ cnt, unsigned int* __restrict__ sPk) {
    int bid = blockIdx.x;
    int phase = bid % 24;
    if (phase < 8) {
        int cb = (bid / 24) * 8 + phase;          // 0..10167
        if (cb < 10000) {
            int row = cb * 4 + (threadIdx.x >> 6);
            int lane = threadIdx.x & 63;
            float2 v = ((const float2*)(x + (size_t)row * 128))[lane];
            float mu = wave_sum(v.x + v.y) * (1.0f / 128.0f);
            float dx = v.x - mu, dy = v.y - mu;
            float var = wave_sum(dx * dx + dy * dy) * (1.0f / 128.0f);
            float rs = rsqrtf(var + 1e-5f);
            float2 gv = ((const float2*)g)[lane];
            float2 bv = ((const float2*)b)[lane];
            float ox = dx * rs * gv.x + bv.x;
            float oy = dy * rs * gv.y + bv.y;
            ushort2 hv, lv;
            hv.x = f2bf(ox); hv.y = f2bf(oy);
            lv.x = f2bf(ox - bf2f(hv.x)); lv.y = f2bf(oy - bf2f(hv.y));
            ((ushort2*)(h0h + (size_t)row * 128))[lane] = hv;
            ((ushort2*)(h0l + (size_t)row * 128))[lane] = lv;
        } else {
            int i = (cb - 10000) * 256 + threadIdx.x;   // 0..43007
            float w; unsigned short *ph, *pl; int idx;
            if (i < 256 * 128) {
                int c = i >> 7, k = i & 127;
                w = (c < 128) ? W0l[c * 128 + k] : W0r[(c - 128) * 128 + k];
                ph = Wt1h; pl = Wt1l; idx = i;
            } else {
                int j = i - 256 * 128;
                int c = j >> 7, k = j & 127;
                w = (c < 40) ? W1l[c * 128 + k] : W1r[(c - 40) * 128 + k];
                ph = Wt2h; pl = Wt2l; idx = j;
            }
            unsigned short hi = f2bf(w);
            ph[idx] = hi;
            pl[idx] = f2bf(w - bf2f(hi));
        }
    } else {
        int gp = bid & 7;                                   // == (phase-8)&7 -> XCD
        int chunk = (bid / 24) * 2 + ((phase - 8) >> 3);    // 0..2541
        if (chunk < N_EDGES / 256) {
            int e = chunk * 256 + threadIdx.x;
            int d = ei[N_EDGES + e];
            int lo = gp * FRANGE;
            if (d >= lo && d < lo + FRANGE) {
                unsigned int pk = (unsigned int)ei[e] | ((unsigned int)f2bf(ew[e]) << 16);
                int rank = atomicAdd(&cnt[d], 1);
                if (rank < BCAP) sPk[(size_t)d * BCAP + rank] = pk;
            }
        }
    }
}

// ---------------- MFMA GEMMs, B staged in LDS (XOR-swizzled) ----------------
// LDS element (c,k) at byte (c*256 + k*2) ^ ((c&7)<<4).
// C/D: col = lane&15, row = (lane>>4)*4 + reg   [HW-verified]

// hl(bf16, bias folded) = h0@W0l^T + b0l (cols 0..127); agg(fp32) = h0@W0r^T
__global__ __launch_bounds__(256) void gemm1_kernel(
        const unsigned short* __restrict__ h0h, const unsigned short* __restrict__ h0l,
        const unsigned short* __restrict__ Wt1h, const unsigned short* __restrict__ Wt1l,
        const float* __restrict__ b0l,
        unsigned short* __restrict__ hl, float* __restrict__ agg) {
    __shared__ unsigned short Bs[2][128 * 128];   // 64 KB
    int tid = threadIdx.x;
    int cBase = blockIdx.y * 128;
    #pragma unroll
    for (int plane = 0; plane < 2; ++plane) {
        const unsigned short* src = plane ? Wt1l : Wt1h;
        char* dst = (char*)Bs[plane];
        #pragma unroll
        for (int i = 0; i < 8; ++i) {
            int gid = i * 256 + tid;
            int c = gid >> 4, kc = gid & 15;
            short8 v = *(const short8*)(src + (size_t)(cBase + c) * 128 + kc * 8);
            int byte = (c * 256 + kc * 16) ^ ((c & 7) << 4);
            *(short8*)(dst + byte) = v;
        }
    }
    __syncthreads();

    int wid = tid >> 6, lane = tid & 63;
    int rBase = (blockIdx.x * 4 + wid) * 32;
    if (rBase < N_NODES) {
        int lr = lane & 15;
        int lk = (lane >> 4) * 8;
        int sw = (lr & 7) << 4;
        const unsigned short* a0h = h0h + (size_t)(rBase + lr) * 128 + lk;
        const unsigned short* a0l = h0l + (size_t)(rBase + lr) * 128 + lk;
        const unsigned short* a1h = a0h + 16 * 128;
        const unsigned short* a1l = a0l + 16 * 128;
        f32x4 acc[2][8] = {};
        #pragma unroll
        for (int ks = 0; ks < 4; ++ks) {
            int kb = ks * 32;
            short8 A0h = *(const short8*)(a0h + kb);
            short8 A0l = *(const short8*)(a0l + kb);
            short8 A1h = *(const short8*)(a1h + kb);
            short8 A1l = *(const short8*)(a1l + kb);
            #pragma unroll
            for (int ct = 0; ct < 8; ++ct) {
                int bb = (((ct * 16 + lr) << 8) + (ks << 6) + ((lane >> 4) << 4)) ^ sw;
                short8 Bh = *(const short8*)((const char*)Bs[0] + bb);
                short8 Bl = *(const short8*)((const char*)Bs[1] + bb);
                acc[0][ct] = __builtin_amdgcn_mfma_f32_16x16x32_bf16(A0h, Bh, acc[0][ct], 0, 0, 0);
                acc[0][ct] = __builtin_amdgcn_mfma_f32_16x16x32_bf16(A0h, Bl, acc[0][ct], 0, 0, 0);
                acc[0][ct] = __builtin_amdgcn_mfma_f32_16x16x32_bf16(A0l, Bh, acc[0][ct], 0, 0, 0);
                acc[1][ct] = __builtin_amdgcn_mfma_f32_16x16x32_bf16(A1h, Bh, acc[1][ct], 0, 0, 0);
                acc[1][ct] = __builtin_amdgcn_mfma_f32_16x16x32_bf16(A1h, Bl, acc[1][ct], 0, 0, 0);
                acc[1][ct] = __builtin_amdgcn_mfma_f32_16x16x32_bf16(A1l, Bh, acc[1][ct], 0, 0, 0);
            }
        }
        int orow = (lane >> 4) * 4;
        #pragma unroll
        for (int rt = 0; rt < 2; ++rt) {
            int row = rBase + rt * 16 + orow;
            #pragma unroll
            for (int ct = 0; ct < 8; ++ct) {
                int col = cBase + ct * 16 + lr;
                if (col < 128) {
                    float bias = b0l[col];
                    #pragma unroll
                    for (int j = 0; j < 4; ++j)
                        hl[(size_t)(row + j) * 128 + col] = f2bf(acc[rt][ct][j] + bias);
                } else {
                    int cc = col - 128;
                    #pragma unroll
                    for (int j = 0; j < 4; ++j)
                        agg[(size_t)(row + j) * 128 + cc] = acc[rt][ct][j];
                }
            }
        }
    }
}

// gl(bf16, bias folded) = h2@W1l^T + b1l (cols 0..39); agg2(fp32) = h2@W1r^T
__global__ __launch_bounds__(256) void gemm2_kernel(
        const unsigned short* __restrict__ h2h, const unsigned short* __restrict__ h2l,
        const unsigned short* __restrict__ Wt2h, const unsigned short* __restrict__ Wt2l,
        const float* __restrict__ b1l,
        unsigned short* __restrict__ gl, float* __restrict__ agg2) {
    __shared__ unsigned short Bs[2][80 * 128];    // 40 KB
    int tid = threadIdx.x;
    #pragma unroll
    for (int plane = 0; plane < 2; ++plane) {
        const unsigned short* src = plane ? Wt2l : Wt2h;
        char* dst = (char*)Bs[plane];
        #pragma unroll
        for (int i = 0; i < 5; ++i) {
            int gid = i * 256 + tid;
            int c = gid >> 4, kc = gid & 15;
            short8 v = *(const short8*)(src + (size_t)c * 128 + kc * 8);
            int byte = (c * 256 + kc * 16) ^ ((c & 7) << 4);
            *(short8*)(dst + byte) = v;
        }
    }
    __syncthreads();

    int wid = tid >> 6, lane = tid & 63;
    int rBase = (blockIdx.x * 4 + wid) * 32;
    if (rBase < N_NODES) {
        int lr = lane & 15;
        int lk = (lane >> 4) * 8;
        int sw = (lr & 7) << 4;
        const unsigned short* a0h = h2h + (size_t)(rBase + lr) * 128 + lk;
        const unsigned short* a0l = h2l + (size_t)(rBase + lr) * 128 + lk;
        const unsigned short* a1h = a0h + 16 * 128;
        const unsigned short* a1l = a0l + 16 * 128;
        f32x4 acc[2][5] = {};
        #pragma unroll
        for (int ks = 0; ks < 4; ++ks) {
            int kb = ks * 32;
            short8 A0h = *(const short8*)(a0h + kb);
            short8 A0l = *(const short8*)(a0l + kb);
            short8 A1h = *(const short8*)(a1h + kb);
            short8 A1l = *(const short8*)(a1l + kb);
            #pragma unroll
            for (int ct = 0; ct < 5; ++ct) {
                int bb = (((ct * 16 + lr) << 8) + (ks << 6) + ((lane >> 4) << 4)) ^ sw;
                short8 Bh = *(const short8*)((const char*)Bs[0] + bb);
                short8 Bl = *(const short8*)((const char*)Bs[1] + bb);
                acc[0][ct] = __builtin_amdgcn_mfma_f32_16x16x32_bf16(A0h, Bh, acc[0][ct], 0, 0, 0);
                acc[0][ct] = __builtin_amdgcn_mfma_f32_16x16x32_bf16(A0h, Bl, acc[0][ct], 0, 0, 0);
                acc[0][ct] = __builtin_amdgcn_mfma_f32_16x16x32_bf16(A0l, Bh, acc[0][ct], 0, 0, 0);
                acc[1][ct] = __builtin_amdgcn_mfma_f32_16x16x32_bf16(A1h, Bh, acc[1][ct], 0, 0, 0);
                acc[1][ct] = __builtin_amdgcn_mfma_f32_16x16x32_bf16(A1h, Bl, acc[1][ct], 0, 0, 0);
                acc[1][ct] = __builtin_amdgcn_mfma_f32_16x16x32_bf16(A1l, Bh, acc[1][ct], 0, 0, 0);
            }
        }
        int orow = (lane >> 4) * 4;
        #pragma unroll
        for (int rt = 0; rt < 2; ++rt) {
            int row = rBase + rt * 16 + orow;
            #pragma unroll
            for (int ct = 0; ct < 5; ++ct) {
                int col = ct * 16 + lr;   // 0..79
                if (col < 40) {
                    float bias = b1l[col];
                    #pragma unroll
                    for (int j = 0; j < 4; ++j)
                        gl[(size_t)(row + j) * 40 + col] = f2bf(acc[rt][ct][j] + bias);
                } else {
                    int cc = col - 40;
                    #pragma unroll
                    for (int j = 0; j < 4; ++j)
                        agg2[(size_t)(row + j) * 40 + cc] = acc[rt][ct][j];
                }
            }
        }
    }
}

// gather (bucket layout) + fused l2norm+LN+relu -> split-bf16 h2; wave per node
__global__ __launch_bounds__(256) void gather1_kernel(const int* __restrict__ cnt,
        const unsigned int* __restrict__ sPk, const unsigned short* __restrict__ hl,
        const float* __restrict__ agg,
        const float* __restrict__ g, const float* __restrict__ b,
        unsigned short* __restrict__ h2h, unsigned short* __restrict__ h2l) {
    int row = blockIdx.x * 4 + (threadIdx.x >> 6);
    int lane = threadIdx.x & 63;
    int n = cnt[row]; n = n > BCAP ? BCAP : n;
    const unsigned int* ep = sPk + (size_t)row * BCAP;
    float2 acc = ((const float2*)(agg + (size_t)row * 128))[lane];  // root term
    int e = 0;
    for (; e + 8 <= n; e += 8) {
        uint4 q0 = *(const uint4*)(ep + e);
        uint4 q1 = *(const uint4*)(ep + e + 4);
        ushort2 u0 = ((const ushort2*)(hl + (size_t)(q0.x & 0xFFFF) * 128))[lane];
        ushort2 u1 = ((const ushort2*)(hl + (size_t)(q0.y & 0xFFFF) * 128))[lane];
        ushort2 u2 = ((const ushort2*)(hl + (size_t)(q0.z & 0xFFFF) * 128))[lane];
        ushort2 u3 = ((const ushort2*)(hl + (size_t)(q0.w & 0xFFFF) * 128))[lane];
        ushort2 u4 = ((const ushort2*)(hl + (size_t)(q1.x & 0xFFFF) * 128))[lane];
        ushort2 u5 = ((const ushort2*)(hl + (size_t)(q1.y & 0xFFFF) * 128))[lane];
        ushort2 u6 = ((const ushort2*)(hl + (size_t)(q1.z & 0xFFFF) * 128))[lane];
        ushort2 u7 = ((const ushort2*)(hl + (size_t)(q1.w & 0xFFFF) * 128))[lane];
        float w0 = bf2f((unsigned short)(q0.x >> 16)), w1 = bf2f((unsigned short)(q0.y >> 16));
        float w2 = bf2f((unsigned short)(q0.z >> 16)), w3 = bf2f((unsigned short)(q0.w >> 16));
        float w4 = bf2f((unsigned short)(q1.x >> 16)), w5 = bf2f((unsigned short)(q1.y >> 16));
        float w6 = bf2f((unsigned short)(q1.z >> 16)), w7 = bf2f((unsigned short)(q1.w >> 16));
        acc.x = fmaf(bf2f(u0.x), w0, acc.x); acc.y = fmaf(bf2f(u0.y), w0, acc.y);
        acc.x = fmaf(bf2f(u1.x), w1, acc.x); acc.y = fmaf(bf2f(u1.y), w1, acc.y);
        acc.x = fmaf(bf2f(u2.x), w2, acc.x); acc.y = fmaf(bf2f(u2.y), w2, acc.y);
        acc.x = fmaf(bf2f(u3.x), w3, acc.x); acc.y = fmaf(bf2f(u3.y), w3, acc.y);
        acc.x = fmaf(bf2f(u4.x), w4, acc.x); acc.y = fmaf(bf2f(u4.y), w4, acc.y);
        acc.x = fmaf(bf2f(u5.x), w5, acc.x); acc.y = fmaf(bf2f(u5.y), w5, acc.y);
        acc.x = fmaf(bf2f(u6.x), w6, acc.x); acc.y = fmaf(bf2f(u6.y), w6, acc.y);
        acc.x = fmaf(bf2f(u7.x), w7, acc.x); acc.y = fmaf(bf2f(u7.y), w7, acc.y);
    }
    for (; e < n; ++e) {
        unsigned int p = ep[e];
        ushort2 u = ((const ushort2*)(hl + (size_t)(p & 0xFFFF) * 128))[lane];
        float w = bf2f((unsigned short)(p >> 16));
        acc.x = fmaf(bf2f(u.x), w, acc.x);
        acc.y = fmaf(bf2f(u.y), w, acc.y);
    }
    float nrm = sqrtf(wave_sum(acc.x * acc.x + acc.y * acc.y));
    float inv = 1.0f / fmaxf(nrm, 1e-12f);
    float vx = acc.x * inv, vy = acc.y * inv;
    float mu = wave_sum(vx + vy) * (1.0f / 128.0f);
    float dx = vx - mu, dy = vy - mu;
    float var = wave_sum(dx * dx + dy * dy) * (1.0f / 128.0f);
    float rs = rsqrtf(var + 1e-5f);
    float2 gv = ((const float2*)g)[lane];
    float2 bv = ((const float2*)b)[lane];
    float ox = fmaxf(dx * rs * gv.x + bv.x, 0.0f);
    float oy = fmaxf(dy * rs * gv.y + bv.y, 0.0f);
    ushort2 hv, lv;
    hv.x = f2bf(ox); hv.y = f2bf(oy);
    lv.x = f2bf(ox - bf2f(hv.x)); lv.y = f2bf(oy - bf2f(hv.y));
    ((ushort2*)(h2h + (size_t)row * 128))[lane] = hv;
    ((ushort2*)(h2l + (size_t)row * 128))[lane] = lv;
}

// gather (bucket layout) + fused l2norm + log_softmax; wave per node, lanes 0..39
__global__ __launch_bounds__(256) void gather2_kernel(const int* __restrict__ cnt,
        const unsigned int* __restrict__ sPk, const unsigned short* __restrict__ gl,
        const float* __restrict__ agg2, float* __restrict__ out) {
    int row = blockIdx.x * 4 + (threadIdx.x >> 6);
    int lane = threadIdx.x & 63;
    bool act = lane < 40;
    int n = cnt[row]; n = n > BCAP ? BCAP : n;
    const unsigned int* ep = sPk + (size_t)row * BCAP;
    float acc = act ? agg2[(size_t)row * 40 + lane] : 0.0f;  // root term
    int e = 0;
    for (; e + 8 <= n; e += 8) {
        uint4 q0 = *(const uint4*)(ep + e);
        uint4 q1 = *(const uint4*)(ep + e + 4);
        if (act) {
            float v0 = bf2f(gl[(size_t)(q0.x & 0xFFFF) * 40 + lane]);
            float v1 = bf2f(gl[(size_t)(q0.y & 0xFFFF) * 40 + lane]);
            float v2 = bf2f(gl[(size_t)(q0.z & 0xFFFF) * 40 + lane]);
            float v3 = bf2f(gl[(size_t)(q0.w & 0xFFFF) * 40 + lane]);
            float v4 = bf2f(gl[(size_t)(q1.x & 0xFFFF) * 40 + lane]);
            float v5 = bf2f(gl[(size_t)(q1.y & 0xFFFF) * 40 + lane]);
            float v6 = bf2f(gl[(size_t)(q1.z & 0xFFFF) * 40 + lane]);
            float v7 = bf2f(gl[(size_t)(q1.w & 0xFFFF) * 40 + lane]);
            acc = fmaf(v0, bf2f((unsigned short)(q0.x >> 16)), acc);
            acc = fmaf(v1, bf2f((unsigned short)(q0.y >> 16)), acc);
            acc = fmaf(v2, bf2f((unsigned short)(q0.z >> 16)), acc);
            acc = fmaf(v3, bf2f((unsigned short)(q0.w >> 16)), acc);
            acc = fmaf(v4, bf2f((unsigned short)(q1.x >> 16)), acc);
            acc = fmaf(v5, bf2f((unsigned short)(q1.y >> 16)), acc);
            acc = fmaf(v6, bf2f((unsigned short)(q1.z >> 16)), acc);
            acc = fmaf(v7, bf2f((unsigned short)(q1.w >> 16)), acc);
        }
    }
    for (; e < n; ++e) {
        unsigned int p = ep[e];
        if (act) {
            float v = bf2f(gl[(size_t)(p & 0xFFFF) * 40 + lane]);
            acc = fmaf(v, bf2f((unsigned short)(p >> 16)), acc);
        }
    }
    float nrm = sqrtf(wave_sum(act ? acc * acc : 0.0f));
    float o = acc / fmaxf(nrm, 1e-12f);
    float m = wave_max(act ? o : -INFINITY);
    float s = wave_sum(act ? expf(o - m) : 0.0f);
    float ls = logf(s);
    if (act) out[(size_t)row * 40 + lane] = o - m - ls;
}

extern "C" void kernel_launch(void* const* d_in, const int* in_sizes, int n_in,
                              void* d_out, int out_size, void* d_ws, size_t ws_size,
                              hipStream_t stream) {
    const float* x    = (const float*)d_in[0];
    const int*   ei   = (const int*)d_in[1];
    const float* ew   = (const float*)d_in[2];
    const float* ln0g = (const float*)d_in[3];
    const float* ln0b = (const float*)d_in[4];
    const float* W0l  = (const float*)d_in[5];
    const float* b0l  = (const float*)d_in[6];
    const float* W0r  = (const float*)d_in[7];
    const float* ln1g = (const float*)d_in[8];
    const float* ln1b = (const float*)d_in[9];
    const float* W1l  = (const float*)d_in[10];
    const float* b1l  = (const float*)d_in[11];
    const float* W1r  = (const float*)d_in[12];
    float* out = (float*)d_out;

    const size_t NBUF = (size_t)N_NODES * 128;  // 5.12M elems
    char* p = (char*)d_ws;
    auto alloc = [&](size_t bytes) { char* r = p; p += (bytes + 255) & ~(size_t)255; return r; };
    float*          agg  = (float*)alloc(NBUF * 4);          // agg / agg2 (fp32)
    unsigned short* hl   = (unsigned short*)alloc(NBUF * 2); // hl / gl (bf16)
    unsigned short* h0h  = (unsigned short*)alloc(NBUF * 2); // h0 hi / h2 hi
    unsigned short* h0l  = (unsigned short*)alloc(NBUF * 2); // h0 lo / h2 lo
    unsigned short* Wt1h = (unsigned short*)alloc(256 * 128 * 2);
    unsigned short* Wt1l = (unsigned short*)alloc(256 * 128 * 2);
    unsigned short* Wt2h = (unsigned short*)alloc(80 * 128 * 2);
    unsigned short* Wt2l = (unsigned short*)alloc(80 * 128 * 2);
    unsigned int*   sPk  = (unsigned int*)alloc((size_t)N_NODES * BCAP * 4); // 10.24 MB buckets
    int*            cnt  = (int*)alloc(N_NODES * 4);
    unsigned short* gl   = hl;    // hl dead after gather1
    float*        agg2   = agg;   // agg dead after gather1

    // 1. zero bucket counters (ws is re-poisoned between runs)
    hipMemsetAsync(cnt, 0, (size_t)N_NODES * 4, stream);
    // 2. fused LN0 + weight prep + bucket-fill (independent phases, interleaved)
    comboFill_kernel<<<NSG * 24, 256, 0, stream>>>(x, ln0g, ln0b, h0h, h0l,
            W0l, W0r, W1l, W1r, Wt1h, Wt1l, Wt2h, Wt2l, ei, ew, cnt, sPk);
    // 3-6. pipeline
    gemm1_kernel<<<dim3(313, 2), 256, 0, stream>>>(h0h, h0l, Wt1h, Wt1l, b0l, hl, agg);
    gather1_kernel<<<N_NODES / 4, 256, 0, stream>>>(cnt, sPk, hl, agg,
                                                    ln1g, ln1b, h0h, h0l);
    gemm2_kernel<<<313, 256, 0, stream>>>(h0h, h0l, Wt2h, Wt2l, b1l, gl, agg2);
    gather2_kernel<<<N_NODES / 4, 256, 0, stream>>>(cnt, sPk, gl, agg2, out);
}